// Round 10
// baseline (127.567 us; speedup 1.0000x reference)
//
#include <hip/hip_runtime.h>

#define HEADS 4
#define NN 256
#define DW 32
#define LOG2E 1.4426950408889634f
// (m-1)*MASKBIG added in log2 domain: m=0 -> -1.44e9 -> exp2() == 0.0f
#define MASKBIG 1.442695e9f

typedef __bf16 bf16x8 __attribute__((ext_vector_type(8)));
typedef float f32x4 __attribute__((ext_vector_type(4)));
typedef float f32x16 __attribute__((ext_vector_type(16)));
typedef unsigned int u32x4 __attribute__((ext_vector_type(4)));
typedef unsigned short ushort4v __attribute__((ext_vector_type(4)));

static __device__ __forceinline__ ushort f2bf(float f) {
  __bf16 h = (__bf16)f;
  ushort r;
  __builtin_memcpy(&r, &h, 2);
  return r;
}

static __device__ __forceinline__ unsigned cvt_pk_bf16(float lo, float hi) {
  unsigned r;
  asm("v_cvt_pk_bf16_f32 %0, %1, %2" : "=v"(r) : "v"(lo), "v"(hi));
  return r;
}

// ---------------------------------------------------------------------------
// Triangle bias in wave-coalesced MFMA-C tile layout, pre-scaled by log2(e):
//   bias2[((((h*8+kb)*4+g)*2+hi)*256 + q)*4 + e] = (x[q,k,:].Wb[h]+bb[h])*LOG2E
// with k = kb*32 + 8*g + 4*hi + e (the 32x32x16 C/D row index r = 4g+e).
// One block per q-row; x[q,:,:] staged to LDS with per-instruction-coalesced
// dwordx4 loads; thread t owns key k=t.
// ---------------------------------------------------------------------------
__global__ __launch_bounds__(256) void bias_kernel(
    const float* __restrict__ x, const float* __restrict__ Wb,
    const float* __restrict__ bb, float* __restrict__ bias2) {
  __shared__ float xs[NN * 36];  // [k][36] pad-36: b128-aligned rows

  const int q = blockIdx.x;
  const int t = threadIdx.x;

  const float* xr = x + q * (NN * DW);
#pragma unroll
  for (int cc = 0; cc < 8; ++cc) {
    const int f = (cc * 256 + t) * 4;  // flat dword index
    const float4 v = *reinterpret_cast<const float4*>(xr + f);
    const int k = f >> 5;
    const int d = f & 31;
    *reinterpret_cast<float4*>(&xs[k * 36 + d]) = v;
  }
  __syncthreads();

  float xv[DW];
#pragma unroll
  for (int c = 0; c < 8; ++c) {
    const float4 v = *reinterpret_cast<const float4*>(&xs[t * 36 + c * 4]);
    xv[c * 4 + 0] = v.x; xv[c * 4 + 1] = v.y;
    xv[c * 4 + 2] = v.z; xv[c * 4 + 3] = v.w;
  }

  const int kb = t >> 5;
  const int c2 = t & 31;
  const int e = c2 & 3;
  const int hi = (c2 >> 2) & 1;
  const int g = c2 >> 3;

#pragma unroll
  for (int h = 0; h < HEADS; ++h) {
    float a0 = 0.f, a1 = 0.f;
#pragma unroll
    for (int d = 0; d < DW; d += 2) {
      a0 += xv[d] * Wb[h * DW + d];        // Wb uniform -> s_loads
      a1 += xv[d + 1] * Wb[h * DW + d + 1];
    }
    bias2[((((h * 8 + kb) * 4 + g) * 2 + hi) * NN + q) * 4 + e] =
        (a0 + a1 + bb[h]) * LOG2E;
  }
}

// ---------------------------------------------------------------------------
// Fused QKV projection + attention, swapped-QK 32x32x16 MFMA structure.
// INSTRUMENTATION + AMORTIZATION ROUND: grid = 256, block = row i, 4 waves;
// the block loops over all 4 heads sequentially (per-head body identical to
// the best-measured r6 kernel: sequential tile(0)/tile(1), bias dbuf, no
// interleave, no XCD swizzle). Effects:
//  - x A-frags + mask loaded ONCE per 4 heads (prologue / 4), one dispatch
//    round, no tail;
//  - dispatch duration ~4x per-block time -> attn finally surfaces in the
//    rocprof top-5 with interpretable counters (at 1 wave/SIMD, VALUBusy
//    directly measures the serial chain's issue density).
//
// S^T = K·Q^T -> lane l holds q = l&31, 16 keys at (r&3)+8*(r>>2)+4*(l>>5).
// Key mask folded into the MFMA C operand in log2 domain (mk[] = mterm).
// Softmax lane-local, exp2-direct. P -> PV A-frags via cvt_pk_bf16 +
// v_permlane32_swap. O C-layout cols = d -> coalesced stores.
// __launch_bounds__(256,3): twice-measured stable envelope (no spills).
// ---------------------------------------------------------------------------
__global__ __launch_bounds__(256, 3) void attn_mfma(
    const float* __restrict__ x, const float* __restrict__ mask,
    const float* __restrict__ Wq, const float* __restrict__ bq,
    const float* __restrict__ Wk, const float* __restrict__ bk,
    const float* __restrict__ Wv, const float* __restrict__ bv,
    const float* __restrict__ bias2, float* __restrict__ out) {
  __shared__ __align__(16) ushort Kq[NN][40];
  __shared__ __align__(16) ushort Vt[DW][264];
  __shared__ __align__(16) float mk[NN];   // holds mterm, not raw mask
  __shared__ __align__(16) float Ls[NN];

  const int i = blockIdx.x;
  const int t = threadIdx.x;
  const int w = t >> 6;
  const int l = t & 63;
  const int lo5 = l & 31;
  const int hi = l >> 5;
  const int lr = l & 15;
  const int lq = l >> 4;
  const int rowbase = w * 64;
  const float scale = 0.17677669529663687f * LOG2E;  // log2e/sqrt(32)

  // ---- x A-fragments for this wave's 64 rows (shared by ALL heads) ----
  bf16x8 af[4];
#pragma unroll
  for (int rt = 0; rt < 4; ++rt) {
    const float* xr = x + (i * NN + rowbase + rt * 16 + lr) * DW + lq * 8;
#pragma unroll
    for (int jj = 0; jj < 8; ++jj) af[rt][jj] = (__bf16)xr[jj];
  }
  // mask -> log2-domain mterm: 0 (keep) or -1.44e9 (masked -> exp2 == 0)
  mk[t] = (mask[i * NN + t] - 1.0f) * MASKBIG;

#pragma unroll 1
  for (int h = 0; h < HEADS; ++h) {
    // Kq/Vt safe to overwrite (all waves past previous head's main loop);
    // also makes mk visible before the first head's main loop.
    __syncthreads();

    // ---- Q phase: Wq frags -> project -> stage into Kq (own band) ----
    {
      bf16x8 wf[2];
#pragma unroll
      for (int nt = 0; nt < 2; ++nt) {
        const float* rq = Wq + (h * DW + nt * 16 + lr) * DW + lq * 8;
#pragma unroll
        for (int jj = 0; jj < 8; ++jj) wf[nt][jj] = (__bf16)rq[jj];
      }
#pragma unroll
      for (int rt = 0; rt < 4; ++rt) {
#pragma unroll
        for (int nt = 0; nt < 2; ++nt) {
          const int dd = nt * 16 + lr;
          f32x4 z = {0.f, 0.f, 0.f, 0.f};
          f32x4 cq =
              __builtin_amdgcn_mfma_f32_16x16x32_bf16(af[rt], wf[nt], z, 0, 0, 0);
          const float bqv = bq[h * DW + dd];
#pragma unroll
          for (int j = 0; j < 4; ++j)
            Kq[rowbase + rt * 16 + lq * 4 + j][dd] =
                f2bf((cq[j] + bqv) * scale);
        }
      }
    }
    // own-wave write->read: compiler inserts lgkmcnt wait; no barrier needed
    bf16x8 qb[2][2];
#pragma unroll
    for (int qt = 0; qt < 2; ++qt)
#pragma unroll
      for (int dh = 0; dh < 2; ++dh)
        qb[qt][dh] =
            *(const bf16x8*)&Kq[rowbase + qt * 32 + lo5][dh * 16 + 8 * hi];

    // ---- K+V phase: overwrite own band with K; stage V transposed ----
    {
      bf16x8 wfk[2], wfv[2];
#pragma unroll
      for (int nt = 0; nt < 2; ++nt) {
        const float* rk = Wk + (h * DW + nt * 16 + lr) * DW + lq * 8;
        const float* rv = Wv + (h * DW + nt * 16 + lr) * DW + lq * 8;
#pragma unroll
        for (int jj = 0; jj < 8; ++jj) {
          wfk[nt][jj] = (__bf16)rk[jj];
          wfv[nt][jj] = (__bf16)rv[jj];
        }
      }
#pragma unroll
      for (int rt = 0; rt < 4; ++rt) {
#pragma unroll
        for (int nt = 0; nt < 2; ++nt) {
          const int dd = nt * 16 + lr;
          f32x4 z = {0.f, 0.f, 0.f, 0.f};
          f32x4 ck =
              __builtin_amdgcn_mfma_f32_16x16x32_bf16(af[rt], wfk[nt], z, 0, 0, 0);
          f32x4 cv =
              __builtin_amdgcn_mfma_f32_16x16x32_bf16(af[rt], wfv[nt], z, 0, 0, 0);
          const float bkv = bk[h * DW + dd];
          const float bvv = bv[h * DW + dd];
#pragma unroll
          for (int j = 0; j < 4; ++j)
            Kq[rowbase + rt * 16 + lq * 4 + j][dd] = f2bf(ck[j] + bkv);
          ushort4v v4;
#pragma unroll
          for (int j = 0; j < 4; ++j) v4[j] = f2bf(cv[j] + bvv);
          *(ushort4v*)&Vt[dd][rowbase + rt * 16 + lq * 4] = v4;
        }
      }
    }
    __syncthreads();  // K/V visible to all waves

    // ---- main loop over 8 key-blocks of 32 (r6 body, sequential tiles) ----
    f32x16 ot[2];
    float lsum[2] = {0.f, 0.f};
#pragma unroll
    for (int qt = 0; qt < 2; ++qt)
#pragma unroll
      for (int r = 0; r < 16; ++r) ot[qt][r] = 0.f;

    const float* btl = bias2 + h * (8 * 4 * 2 * NN * 4) + hi * (NN * 4);

    // prefetch bias tile (kb=0, qt=0)
    f32x4 bc[4], bn[4];
    {
      const float* p = btl + (rowbase + lo5) * 4;
#pragma unroll
      for (int g = 0; g < 4; ++g) bc[g] = *(const f32x4*)(p + g * (2 * NN * 4));
    }

#pragma unroll 1
    for (int kb = 0; kb < 8; ++kb) {
      const int kbase = kb * 32;
      const bf16x8 ka0 = *(const bf16x8*)&Kq[kbase + lo5][8 * hi];
      const bf16x8 ka1 = *(const bf16x8*)&Kq[kbase + lo5][16 + 8 * hi];
      const bf16x8 va0 = *(const bf16x8*)&Vt[lo5][kbase + 8 * hi];
      const bf16x8 va1 = *(const bf16x8*)&Vt[lo5][kbase + 16 + 8 * hi];
      float4 mt4[4];
#pragma unroll
      for (int g = 0; g < 4; ++g)
        mt4[g] = *(const float4*)&mk[kbase + 4 * hi + 8 * g];

      auto tile = [&](const int qt, const f32x4 bcur[4]) {
        // C operand = bias + mterm (mask folded in log2 domain)
        f32x16 cc;
#pragma unroll
        for (int g = 0; g < 4; ++g)
#pragma unroll
          for (int e = 0; e < 4; ++e)
            cc[g * 4 + e] = bcur[g][e] + (&mt4[g].x)[e];
        __builtin_amdgcn_s_setprio(1);
        f32x16 st =
            __builtin_amdgcn_mfma_f32_32x32x16_bf16(ka0, qb[qt][0], cc, 0, 0, 0);
        st = __builtin_amdgcn_mfma_f32_32x32x16_bf16(ka1, qb[qt][1], st, 0, 0, 0);
        __builtin_amdgcn_s_setprio(0);

#pragma unroll
        for (int r = 0; r < 16; ++r) st[r] = __builtin_amdgcn_exp2f(st[r]);
        float s0 = (st[0] + st[1]) + (st[2] + st[3]);
        float s1 = (st[4] + st[5]) + (st[6] + st[7]);
        float s2 = (st[8] + st[9]) + (st[10] + st[11]);
        float s3 = (st[12] + st[13]) + (st[14] + st[15]);
        lsum[qt] += (s0 + s1) + (s2 + s3);

#pragma unroll
        for (int half = 0; half < 2; ++half) {
          const int b0 = half * 8;
          unsigned w0, w1, w2, w3;
          {
            unsigned A = cvt_pk_bf16(st[b0 + 0], st[b0 + 1]);
            unsigned B = cvt_pk_bf16(st[b0 + 4], st[b0 + 5]);
            asm volatile("v_permlane32_swap_b32 %0, %1" : "+v"(A), "+v"(B));
            w0 = A; w2 = B;
          }
          {
            unsigned A = cvt_pk_bf16(st[b0 + 2], st[b0 + 3]);
            unsigned B = cvt_pk_bf16(st[b0 + 6], st[b0 + 7]);
            asm volatile("v_permlane32_swap_b32 %0, %1" : "+v"(A), "+v"(B));
            w1 = A; w3 = B;
          }
          u32x4 words = {w0, w1, w2, w3};
          const bf16x8 pf = __builtin_bit_cast(bf16x8, words);
          __builtin_amdgcn_s_setprio(1);
          ot[qt] = __builtin_amdgcn_mfma_f32_32x32x16_bf16(
              pf, half ? va1 : va0, ot[qt], 0, 0, 0);
          __builtin_amdgcn_s_setprio(0);
        }
      };

      // qt = 0: prefetch (kb, qt=1) first, then compute
      {
        const float* p = btl + kb * (8 * NN * 4) + (rowbase + 32 + lo5) * 4;
#pragma unroll
        for (int g = 0; g < 4; ++g) bn[g] = *(const f32x4*)(p + g * (2 * NN * 4));
        tile(0, bc);
#pragma unroll
        for (int g = 0; g < 4; ++g) bc[g] = bn[g];
      }
      // qt = 1: prefetch (kb+1, qt=0) (wrapped; unused on last), then compute
      {
        const int kbn = (kb + 1) & 7;
        const float* p = btl + kbn * (8 * NN * 4) + (rowbase + lo5) * 4;
#pragma unroll
        for (int g = 0; g < 4; ++g) bn[g] = *(const f32x4*)(p + g * (2 * NN * 4));
        tile(1, bc);
#pragma unroll
        for (int g = 0; g < 4; ++g) bc[g] = bn[g];
      }
    }

    // ---- denominators: lane-local + cross-half add (wave-local LDS) ----
#pragma unroll
    for (int qt = 0; qt < 2; ++qt) {
      const float ls = lsum[qt] + __shfl_xor(lsum[qt], 32);
      Ls[rowbase + qt * 32 + lo5] = 1.0f / ls;  // both halves same value
    }

    // ---- normalize + store (C-layout cols = d -> coalesced segments) ----
#pragma unroll
    for (int qt = 0; qt < 2; ++qt)
#pragma unroll
      for (int r = 0; r < 16; ++r) {
        const int qp = (r & 3) + 8 * (r >> 2) + 4 * hi;
        const int qrow = rowbase + qt * 32 + qp;
        out[((i * NN + qrow) * HEADS + h) * DW + lo5] = ot[qt][r] * Ls[qrow];
      }
  }
}

extern "C" void kernel_launch(void* const* d_in, const int* in_sizes, int n_in,
                              void* d_out, int out_size, void* d_ws,
                              size_t ws_size, hipStream_t stream) {
  const float* x    = (const float*)d_in[0];
  const float* mask = (const float*)d_in[1];
  const float* Wq   = (const float*)d_in[2];
  const float* bq   = (const float*)d_in[3];
  const float* Wk   = (const float*)d_in[4];
  const float* bk   = (const float*)d_in[5];
  const float* Wv   = (const float*)d_in[6];
  const float* bv   = (const float*)d_in[7];
  const float* Wb   = (const float*)d_in[8];
  const float* bb   = (const float*)d_in[9];
  float* out = (float*)d_out;
  float* bias2 = (float*)d_ws;  // HEADS*8*4*2*256*4 floats = 1 MB

  bias_kernel<<<NN, 256, 0, stream>>>(x, Wb, bb, bias2);
  attn_mfma<<<NN, 256, 0, stream>>>(x, mask, Wq, bq, Wk, bk, Wv, bv,
                                    bias2, out);
}

// Round 11
// 116.416 us; speedup vs baseline: 1.0958x; 1.0958x over previous
//
#include <hip/hip_runtime.h>

#define HEADS 4
#define NN 256
#define DW 32
#define LOG2E 1.4426950408889634f
// (m-1)*MASKBIG added in log2 domain: m=0 -> -1.44e9 -> exp2() == 0.0f
#define MASKBIG 1.442695e9f

typedef __bf16 bf16x8 __attribute__((ext_vector_type(8)));
typedef float f32x4 __attribute__((ext_vector_type(4)));
typedef float f32x16 __attribute__((ext_vector_type(16)));
typedef unsigned int u32x4 __attribute__((ext_vector_type(4)));
typedef unsigned short ushort4v __attribute__((ext_vector_type(4)));

static __device__ __forceinline__ ushort f2bf(float f) {
  __bf16 h = (__bf16)f;
  ushort r;
  __builtin_memcpy(&r, &h, 2);
  return r;
}

static __device__ __forceinline__ unsigned cvt_pk_bf16(float lo, float hi) {
  unsigned r;
  asm("v_cvt_pk_bf16_f32 %0, %1, %2" : "=v"(r) : "v"(lo), "v"(hi));
  return r;
}

// ---------------------------------------------------------------------------
// Triangle bias in wave-coalesced MFMA-C tile layout, pre-scaled by log2(e):
//   bias2[((((h*8+kb)*4+g)*2+hi)*256 + q)*4 + e] = (x[q,k,:].Wb[h]+bb[h])*LOG2E
// with k = kb*32 + 8*g + 4*hi + e (the 32x32x16 C/D row index r = 4g+e).
// One block per q-row; x[q,:,:] staged to LDS with per-instruction-coalesced
// dwordx4 loads; thread t owns key k=t.
// ---------------------------------------------------------------------------
__global__ __launch_bounds__(256) void bias_kernel(
    const float* __restrict__ x, const float* __restrict__ Wb,
    const float* __restrict__ bb, float* __restrict__ bias2) {
  __shared__ float xs[NN * 36];  // [k][36] pad-36: b128-aligned rows

  const int q = blockIdx.x;
  const int t = threadIdx.x;

  const float* xr = x + q * (NN * DW);
#pragma unroll
  for (int cc = 0; cc < 8; ++cc) {
    const int f = (cc * 256 + t) * 4;  // flat dword index
    const float4 v = *reinterpret_cast<const float4*>(xr + f);
    const int k = f >> 5;
    const int d = f & 31;
    *reinterpret_cast<float4*>(&xs[k * 36 + d]) = v;
  }
  __syncthreads();

  float xv[DW];
#pragma unroll
  for (int c = 0; c < 8; ++c) {
    const float4 v = *reinterpret_cast<const float4*>(&xs[t * 36 + c * 4]);
    xv[c * 4 + 0] = v.x; xv[c * 4 + 1] = v.y;
    xv[c * 4 + 2] = v.z; xv[c * 4 + 3] = v.w;
  }

  const int kb = t >> 5;
  const int c2 = t & 31;
  const int e = c2 & 3;
  const int hi = (c2 >> 2) & 1;
  const int g = c2 >> 3;

#pragma unroll
  for (int h = 0; h < HEADS; ++h) {
    float a0 = 0.f, a1 = 0.f;
#pragma unroll
    for (int d = 0; d < DW; d += 2) {
      a0 += xv[d] * Wb[h * DW + d];        // Wb uniform -> s_loads
      a1 += xv[d + 1] * Wb[h * DW + d + 1];
    }
    bias2[((((h * 8 + kb) * 4 + g) * 2 + hi) * NN + q) * 4 + e] =
        (a0 + a1 + bb[h]) * LOG2E;
  }
}

// one tile of the main loop, fully static (no arrays through pointers):
// QT = 0/1 literal; OT/LS = named f32x16/float accumulators.
#define TILE_BODY(QT, QB0, QB1, OT, LS)                                       \
  {                                                                           \
    const float* p =                                                          \
        btl + kb * (8 * NN * 4) + (rowbase + (QT)*32 + lo5) * 4;              \
    const f32x4 b0 = *(const f32x4*)(p);                                      \
    const f32x4 b1 = *(const f32x4*)(p + 2 * NN * 4);                         \
    const f32x4 b2 = *(const f32x4*)(p + 4 * NN * 4);                         \
    const f32x4 b3 = *(const f32x4*)(p + 6 * NN * 4);                         \
    f32x16 cc;                                                                \
    cc[0] = b0[0] + mt0[0]; cc[1] = b0[1] + mt0[1];                           \
    cc[2] = b0[2] + mt0[2]; cc[3] = b0[3] + mt0[3];                           \
    cc[4] = b1[0] + mt1[0]; cc[5] = b1[1] + mt1[1];                           \
    cc[6] = b1[2] + mt1[2]; cc[7] = b1[3] + mt1[3];                           \
    cc[8] = b2[0] + mt2[0]; cc[9] = b2[1] + mt2[1];                           \
    cc[10] = b2[2] + mt2[2]; cc[11] = b2[3] + mt2[3];                         \
    cc[12] = b3[0] + mt3[0]; cc[13] = b3[1] + mt3[1];                         \
    cc[14] = b3[2] + mt3[2]; cc[15] = b3[3] + mt3[3];                         \
    __builtin_amdgcn_s_setprio(1);                                            \
    f32x16 st = __builtin_amdgcn_mfma_f32_32x32x16_bf16(ka0, QB0, cc, 0, 0, 0);\
    st = __builtin_amdgcn_mfma_f32_32x32x16_bf16(ka1, QB1, st, 0, 0, 0);      \
    __builtin_amdgcn_s_setprio(0);                                            \
    _Pragma("unroll")                                                         \
    for (int r = 0; r < 16; ++r) st[r] = __builtin_amdgcn_exp2f(st[r]);       \
    {                                                                         \
      float s0 = (st[0] + st[1]) + (st[2] + st[3]);                           \
      float s1 = (st[4] + st[5]) + (st[6] + st[7]);                           \
      float s2 = (st[8] + st[9]) + (st[10] + st[11]);                         \
      float s3 = (st[12] + st[13]) + (st[14] + st[15]);                       \
      LS += (s0 + s1) + (s2 + s3);                                            \
    }                                                                         \
    {                                                                         \
      unsigned A0 = cvt_pk_bf16(st[0], st[1]);                                \
      unsigned B0 = cvt_pk_bf16(st[4], st[5]);                                \
      asm volatile("v_permlane32_swap_b32 %0, %1" : "+v"(A0), "+v"(B0));      \
      unsigned A1 = cvt_pk_bf16(st[2], st[3]);                                \
      unsigned B1 = cvt_pk_bf16(st[6], st[7]);                                \
      asm volatile("v_permlane32_swap_b32 %0, %1" : "+v"(A1), "+v"(B1));      \
      u32x4 words = {A0, A1, B0, B1};                                         \
      const bf16x8 pf = __builtin_bit_cast(bf16x8, words);                    \
      __builtin_amdgcn_s_setprio(1);                                          \
      OT = __builtin_amdgcn_mfma_f32_32x32x16_bf16(pf, va0, OT, 0, 0, 0);     \
      __builtin_amdgcn_s_setprio(0);                                          \
    }                                                                         \
    {                                                                         \
      unsigned A0 = cvt_pk_bf16(st[8], st[9]);                                \
      unsigned B0 = cvt_pk_bf16(st[12], st[13]);                              \
      asm volatile("v_permlane32_swap_b32 %0, %1" : "+v"(A0), "+v"(B0));      \
      unsigned A1 = cvt_pk_bf16(st[10], st[11]);                              \
      unsigned B1 = cvt_pk_bf16(st[14], st[15]);                              \
      asm volatile("v_permlane32_swap_b32 %0, %1" : "+v"(A1), "+v"(B1));      \
      u32x4 words = {A0, A1, B0, B1};                                         \
      const bf16x8 pf = __builtin_bit_cast(bf16x8, words);                    \
      __builtin_amdgcn_s_setprio(1);                                          \
      OT = __builtin_amdgcn_mfma_f32_32x32x16_bf16(pf, va1, OT, 0, 0, 0);     \
      __builtin_amdgcn_s_setprio(0);                                          \
    }                                                                         \
  }

// ---------------------------------------------------------------------------
// Fused QKV projection + attention, swapped-QK 32x32x16 MFMA structure.
// grid = 1024 (block = one (i,h)), 256 threads / 4 waves; r6 shape (best
// measured), but the main loop is FULLY STATIC: no lambda, no pointer-passed
// register arrays, no bias prefetch buffers. r10's counters showed ~7MB of
// scratch traffic (WRITE 40.4MB vs 33.5MB out) from the tile(qt, bcur[])
// lambda -- rule-#20 demotion. Removing all dynamic indexing + shrinking the
// live set (~110 regs) targets genuine 4 blocks/CU (LDS 38.5KB x4 = 154KB,
// VGPR 512/110 >= 4 waves/SIMD) with zero scratch; bias loads go straight
// into the MFMA C operand and their ~250cy L2 latency is shared across 4
// resident waves.
//
// S^T = K·Q^T -> lane l holds q = l&31, 16 keys at (r&3)+8*(r>>2)+4*(l>>5).
// Key mask folded into the MFMA C operand in log2 domain (mk[] = mterm).
// Softmax lane-local, exp2-direct. P -> PV A-frags via cvt_pk_bf16 +
// v_permlane32_swap. O C-layout cols = d -> coalesced stores.
// __launch_bounds__(256,3): stable envelope (min-arg 4 spills: r4, r8).
// ---------------------------------------------------------------------------
__global__ __launch_bounds__(256, 3) void attn_mfma(
    const float* __restrict__ x, const float* __restrict__ mask,
    const float* __restrict__ Wq, const float* __restrict__ bq,
    const float* __restrict__ Wk, const float* __restrict__ bk,
    const float* __restrict__ Wv, const float* __restrict__ bv,
    const float* __restrict__ bias2, float* __restrict__ out) {
  __shared__ __align__(16) ushort Kq[NN][40];
  __shared__ __align__(16) ushort Vt[DW][264];
  __shared__ __align__(16) float mk[NN];   // holds mterm, not raw mask
  __shared__ __align__(16) float Ls[NN];

  const int bid = blockIdx.x;
  const int i = bid >> 2;
  const int h = bid & 3;
  const int t = threadIdx.x;
  const int w = t >> 6;
  const int l = t & 63;
  const int lo5 = l & 31;
  const int hi = l >> 5;
  const int lr = l & 15;
  const int lq = l >> 4;
  const int rowbase = w * 64;
  const float scale = 0.17677669529663687f * LOG2E;  // log2e/sqrt(32)

  // ---- x A-fragments for this wave's 64 rows (reused for Q,K,V) ----
  bf16x8 af[4];
#pragma unroll
  for (int rt = 0; rt < 4; ++rt) {
    const float* xr = x + (i * NN + rowbase + rt * 16 + lr) * DW + lq * 8;
#pragma unroll
    for (int jj = 0; jj < 8; ++jj) af[rt][jj] = (__bf16)xr[jj];
  }

  // ---- Q phase: Wq frags -> project -> stage into Kq (own band) ----
  {
    bf16x8 wf[2];
#pragma unroll
    for (int nt = 0; nt < 2; ++nt) {
      const float* rq = Wq + (h * DW + nt * 16 + lr) * DW + lq * 8;
#pragma unroll
      for (int jj = 0; jj < 8; ++jj) wf[nt][jj] = (__bf16)rq[jj];
    }
#pragma unroll
    for (int rt = 0; rt < 4; ++rt) {
#pragma unroll
      for (int nt = 0; nt < 2; ++nt) {
        const int dd = nt * 16 + lr;
        f32x4 z = {0.f, 0.f, 0.f, 0.f};
        f32x4 cq =
            __builtin_amdgcn_mfma_f32_16x16x32_bf16(af[rt], wf[nt], z, 0, 0, 0);
        const float bqv = bq[h * DW + dd];
#pragma unroll
        for (int j = 0; j < 4; ++j)
          Kq[rowbase + rt * 16 + lq * 4 + j][dd] = f2bf((cq[j] + bqv) * scale);
      }
    }
  }
  // own-wave write->read: compiler inserts lgkmcnt wait; no barrier needed
  bf16x8 qb00, qb01, qb10, qb11;
  qb00 = *(const bf16x8*)&Kq[rowbase + lo5][8 * hi];
  qb01 = *(const bf16x8*)&Kq[rowbase + lo5][16 + 8 * hi];
  qb10 = *(const bf16x8*)&Kq[rowbase + 32 + lo5][8 * hi];
  qb11 = *(const bf16x8*)&Kq[rowbase + 32 + lo5][16 + 8 * hi];

  // ---- K+V phase: overwrite own band with K; stage V transposed ----
  {
    bf16x8 wfk[2], wfv[2];
#pragma unroll
    for (int nt = 0; nt < 2; ++nt) {
      const float* rk = Wk + (h * DW + nt * 16 + lr) * DW + lq * 8;
      const float* rv = Wv + (h * DW + nt * 16 + lr) * DW + lq * 8;
#pragma unroll
      for (int jj = 0; jj < 8; ++jj) {
        wfk[nt][jj] = (__bf16)rk[jj];
        wfv[nt][jj] = (__bf16)rv[jj];
      }
    }
#pragma unroll
    for (int rt = 0; rt < 4; ++rt) {
#pragma unroll
      for (int nt = 0; nt < 2; ++nt) {
        const int dd = nt * 16 + lr;
        f32x4 z = {0.f, 0.f, 0.f, 0.f};
        f32x4 ck =
            __builtin_amdgcn_mfma_f32_16x16x32_bf16(af[rt], wfk[nt], z, 0, 0, 0);
        f32x4 cv =
            __builtin_amdgcn_mfma_f32_16x16x32_bf16(af[rt], wfv[nt], z, 0, 0, 0);
        const float bkv = bk[h * DW + dd];
        const float bvv = bv[h * DW + dd];
#pragma unroll
        for (int j = 0; j < 4; ++j)
          Kq[rowbase + rt * 16 + lq * 4 + j][dd] = f2bf(ck[j] + bkv);
        ushort4v v4;
#pragma unroll
        for (int j = 0; j < 4; ++j) v4[j] = f2bf(cv[j] + bvv);
        *(ushort4v*)&Vt[dd][rowbase + rt * 16 + lq * 4] = v4;
      }
    }
  }
  // mask -> log2-domain mterm: 0 (keep) or -1.44e9 (masked -> exp2 == 0)
  mk[t] = (mask[i * NN + t] - 1.0f) * MASKBIG;
  __syncthreads();  // single barrier: K/V/mterm visible to all waves

  // ---- main loop over 8 key-blocks of 32; fully static bodies ----
  f32x16 ot0, ot1;
  float lsum0 = 0.f, lsum1 = 0.f;
#pragma unroll
  for (int r = 0; r < 16; ++r) { ot0[r] = 0.f; ot1[r] = 0.f; }

  const float* btl = bias2 + h * (8 * 4 * 2 * NN * 4) + hi * (NN * 4);

#pragma unroll 1
  for (int kb = 0; kb < 8; ++kb) {
    const int kbase = kb * 32;
    const bf16x8 ka0 = *(const bf16x8*)&Kq[kbase + lo5][8 * hi];
    const bf16x8 ka1 = *(const bf16x8*)&Kq[kbase + lo5][16 + 8 * hi];
    const bf16x8 va0 = *(const bf16x8*)&Vt[lo5][kbase + 8 * hi];
    const bf16x8 va1 = *(const bf16x8*)&Vt[lo5][kbase + 16 + 8 * hi];
    const f32x4 mt0 = *(const f32x4*)&mk[kbase + 4 * hi];
    const f32x4 mt1 = *(const f32x4*)&mk[kbase + 4 * hi + 8];
    const f32x4 mt2 = *(const f32x4*)&mk[kbase + 4 * hi + 16];
    const f32x4 mt3 = *(const f32x4*)&mk[kbase + 4 * hi + 24];

    TILE_BODY(0, qb00, qb01, ot0, lsum0)
    TILE_BODY(1, qb10, qb11, ot1, lsum1)
  }

  // ---- denominators: lane-local + cross-half add, broadcast via LDS ----
  {
    const float l0 = lsum0 + __shfl_xor(lsum0, 32);
    const float l1 = lsum1 + __shfl_xor(lsum1, 32);
    Ls[rowbase + lo5] = 1.0f / l0;        // both halves write same value
    Ls[rowbase + 32 + lo5] = 1.0f / l1;
  }

  // ---- normalize + store (C-layout cols = d -> coalesced 128B segments) ----
#pragma unroll
  for (int r = 0; r < 16; ++r) {
    const int qp = (r & 3) + 8 * (r >> 2) + 4 * hi;
    const int q0 = rowbase + qp;
    const int q1 = rowbase + 32 + qp;
    out[((i * NN + q0) * HEADS + h) * DW + lo5] = ot0[r] * Ls[q0];
    out[((i * NN + q1) * HEADS + h) * DW + lo5] = ot1[r] * Ls[q1];
  }
}

extern "C" void kernel_launch(void* const* d_in, const int* in_sizes, int n_in,
                              void* d_out, int out_size, void* d_ws,
                              size_t ws_size, hipStream_t stream) {
  const float* x    = (const float*)d_in[0];
  const float* mask = (const float*)d_in[1];
  const float* Wq   = (const float*)d_in[2];
  const float* bq   = (const float*)d_in[3];
  const float* Wk   = (const float*)d_in[4];
  const float* bk   = (const float*)d_in[5];
  const float* Wv   = (const float*)d_in[6];
  const float* bv   = (const float*)d_in[7];
  const float* Wb   = (const float*)d_in[8];
  const float* bb   = (const float*)d_in[9];
  float* out = (float*)d_out;
  float* bias2 = (float*)d_ws;  // HEADS*8*4*2*256*4 floats = 1 MB

  bias_kernel<<<NN, 256, 0, stream>>>(x, Wb, bb, bias2);
  attn_mfma<<<NN * HEADS, 256, 0, stream>>>(x, mask, Wq, bq, Wk, bk, Wv, bv,
                                            bias2, out);
}